// Round 1
// 289.429 us; speedup vs baseline: 1.0495x; 1.0495x over previous
//
#include <hip/hip_runtime.h>
#include <hip/hip_fp16.h>

#define B_   8
#define S_   4096
#define DD_  1024   // dst nodes
#define DIM_ 512
#define SCALE 0.044194173824159216f  // 1/sqrt(512)

typedef __bf16 bf16x8 __attribute__((ext_vector_type(8)));
typedef float  floatx4 __attribute__((ext_vector_type(4)));

__device__ inline unsigned short f2bf(float f) {
    union { float f; unsigned int u; } v; v.f = f;
    unsigned int r = v.u + 0x7fffu + ((v.u >> 16) & 1u);  // RNE
    return (unsigned short)(r >> 16);
}
__device__ inline float bf2f(unsigned short h) {
    union { unsigned int u; float f; } v; v.u = ((unsigned int)h) << 16;
    return v.f;
}
__device__ inline uint4 cvt8(const float* __restrict__ g) {
    float4 f0 = *(const float4*)g;
    float4 f1 = *(const float4*)(g + 4);
    unsigned short tmp[8] = {f2bf(f0.x), f2bf(f0.y), f2bf(f0.z), f2bf(f0.w),
                             f2bf(f1.x), f2bf(f1.y), f2bf(f1.z), f2bf(f1.w)};
    return *(const uint4*)tmp;
}
// async global->LDS, 16B per lane; lds base must be wave-uniform
__device__ inline void async16(unsigned short* lds, const unsigned short* g) {
    __builtin_amdgcn_global_load_lds(
        (const __attribute__((address_space(1))) void*)g,
        (__attribute__((address_space(3))) void*)lds, 16, 0, 0);
}

// ---------------------------------------------------------------------------
// 128x128xK mainloop, BK=32, 256 threads (2x2 waves, each 4x4 MFMA tiles).
// Double-buffered LDS (As/Bs each [2][128][32] halfwords = 16 KB): next
// K-tile's loads are ISSUED before this tile's ds_read+MFMA, so the barrier's
// vmcnt(0) drain lands after compute instead of right after issue.
// Bank swizzle: physical 16B slot = logical slot ^ ((row>>1)&3). Applied by
// permuting the per-lane GLOBAL source column (LDS dest stays linear for
// global_load_lds) and XORing the ds_read address with the same involution
// (which folds to a per-lane constant since (row>>1)&3 == (fr>>1)&3).
// Without it, the 64B row stride makes 8-lane b128 issue groups alias 4-way
// (measured 4.2M SQ_LDS_BANK_CONFLICT = +4 cyc per ds_read_b128).
// AF32/BF32: 1 = operand is fp32 (stage via cvt8 store), 0 = bf16 (async16).
// ---------------------------------------------------------------------------
template <int AF32, int BF32>
__device__ inline void mainloop(unsigned short* As, unsigned short* Bs,
                                const void* Ap, size_t lda,
                                const void* Bp, size_t ldb,
                                int kIters, floatx4 (&acc)[4][4]) {
    const int t = threadIdx.x, lane = t & 63, wave = t >> 6;
    const int rA = t >> 2;
    const int cA = ((t & 3) ^ ((t >> 3) & 3)) * 8;      // swizzled source col
    const int mrow = (wave >> 1) * 64, ncol = (wave & 1) * 64;
    const int fr = lane & 15, fk = (lane >> 4) * 8;
    const int swz = (((fk >> 3) ^ ((fr >> 1) & 3)) << 3); // physical k-offset

    const unsigned short* gA16 = nullptr; const float* gA32 = nullptr;
    const unsigned short* gB16 = nullptr; const float* gB32 = nullptr;
    if (AF32) gA32 = (const float*)Ap + (size_t)rA * lda + cA;
    else      gA16 = (const unsigned short*)Ap + (size_t)rA * lda + cA;
    if (BF32) gB32 = (const float*)Bp + (size_t)rA * ldb + cA;
    else      gB16 = (const unsigned short*)Bp + (size_t)rA * ldb + cA;

    unsigned short* ldsA = As + wave * 512;   // halfwords; rows 64..127 at +2048
    unsigned short* ldsB = Bs + wave * 512;

    auto stage = [&](int buf) {
        const int o = buf * 4096;             // buffer stride: 128*32 halfwords
        if (AF32) {
            *(uint4*)&As[o + t * 8]        = cvt8(gA32);
            *(uint4*)&As[o + 2048 + t * 8] = cvt8(gA32 + 64 * lda);
            gA32 += 32;
        } else {
            async16(ldsA + o,        gA16);
            async16(ldsA + o + 2048, gA16 + 64 * lda);
            gA16 += 32;
        }
        if (BF32) {
            *(uint4*)&Bs[o + t * 8]        = cvt8(gB32);
            *(uint4*)&Bs[o + 2048 + t * 8] = cvt8(gB32 + 64 * ldb);
            gB32 += 32;
        } else {
            async16(ldsB + o,        gB16);
            async16(ldsB + o + 2048, gB16 + 64 * ldb);
            gB16 += 32;
        }
    };

    stage(0);
    __syncthreads();                          // tile 0 resident
    for (int kt = 0; kt < kIters; ++kt) {
        if (kt + 1 < kIters) stage((kt + 1) & 1);   // issue next tile early
        const int cur = (kt & 1) * 4096;
        bf16x8 af[4], bfr[4];
#pragma unroll
        for (int i = 0; i < 4; ++i)
            af[i] = *(const bf16x8*)&As[cur + (mrow + i * 16 + fr) * 32 + swz];
#pragma unroll
        for (int j = 0; j < 4; ++j)
            bfr[j] = *(const bf16x8*)&Bs[cur + (ncol + j * 16 + fr) * 32 + swz];
#pragma unroll
        for (int i = 0; i < 4; ++i)
#pragma unroll
            for (int j = 0; j < 4; ++j)
                acc[i][j] = __builtin_amdgcn_mfma_f32_16x16x32_bf16(af[i], bfr[j],
                                                                    acc[i][j], 0, 0, 0);
        __syncthreads();   // drains this iter's stage (vmcnt) + all ds_reads
    }
}

#define EPILOGUE_COORDS                                     \
    const int lane = threadIdx.x & 63, wave = threadIdx.x >> 6; \
    const int mrow = (wave >> 1) * 64, ncol = (wave & 1) * 64;  \
    const int col = lane & 15, q = lane >> 4;

#define ACC_INIT                                            \
    floatx4 acc[4][4];                                      \
    _Pragma("unroll") for (int i = 0; i < 4; ++i)           \
        _Pragma("unroll") for (int j = 0; j < 4; ++j)       \
            acc[i][j] = (floatx4){0.f, 0.f, 0.f, 0.f};

// ---------------------------------------------------------------------------
// k_prep: srcb = bf16(src)  (dst conversion now folded into k_dstWr<1,1>)
// ---------------------------------------------------------------------------
__global__ __launch_bounds__(256) void k_prep(const float* __restrict__ src,
                                              unsigned short* __restrict__ srcb) {
    const size_t idx = ((size_t)blockIdx.x * 256 + threadIdx.x) * 8;
    *(uint4*)&srcb[idx] = cvt8(src + idx);
}

// ---------------------------------------------------------------------------
// k_dstWr: DW[b*dd][d] = SCALE * sum_e dst[b*dd][e] * Wr[d][e]
// (logits = src . DW^T — W_route factored onto the small dst side)
// Both operands fp32, converted in-staging (same RNE path as before).
// ---------------------------------------------------------------------------
__global__ __launch_bounds__(256) void k_dstWr(const float* __restrict__ dst,
                                               const float* __restrict__ Wr,
                                               unsigned short* __restrict__ DW) {
    __shared__ unsigned short As[2 * 128 * 32];
    __shared__ unsigned short Bs[2 * 128 * 32];
    const int n0 = blockIdx.x * 128, m0 = blockIdx.y * 128;
    ACC_INIT
    mainloop<1, 1>(As, Bs, dst + (size_t)m0 * DIM_, DIM_,
                   Wr + (size_t)n0 * DIM_, DIM_, DIM_ / 32, acc);
    EPILOGUE_COORDS
#pragma unroll
    for (int i = 0; i < 4; ++i)
#pragma unroll
        for (int j = 0; j < 4; ++j)
#pragma unroll
            for (int r = 0; r < 4; ++r)
                DW[(size_t)(m0 + mrow + i * 16 + q * 4 + r) * DIM_ +
                   n0 + ncol + j * 16 + col] = f2bf(acc[i][j][r] * SCALE);
}

// ---------------------------------------------------------------------------
// k_logitsT: LT[dd][s] = exp(DW[dd][:] . srcb[s][:]) -> bf16  (per batch)
// pure async16 both sides. XCD swizzle: xcd = b; s-tile slow (B L2-hot).
// Epilogue writes per-(b, dd-tile) column sums Lpart (fp32).
// ---------------------------------------------------------------------------
__global__ __launch_bounds__(256) void k_logitsT(const unsigned short* __restrict__ DW,
                                                 const unsigned short* __restrict__ srcb,
                                                 unsigned short* __restrict__ LTb,
                                                 float* __restrict__ Lpart) {
    __shared__ unsigned short As[2 * 128 * 32];
    __shared__ unsigned short Bs[2 * 128 * 32];
    __shared__ float csum[8][128];
    const int n = blockIdx.x;
    const int b = n & 7;          // -> XCD
    const int rem = n >> 3;       // [0,256)
    const int xs = rem >> 3;      // s-tile [0,32), changes slowly (B hot)
    const int yd = rem & 7;       // dd-tile [0,8)
    const int n0 = xs * 128, m0 = yd * 128;
    ACC_INIT
    mainloop<0, 0>(As, Bs,
                   DW + (size_t)b * DD_ * DIM_ + (size_t)m0 * DIM_, DIM_,
                   srcb + (size_t)b * S_ * DIM_ + (size_t)n0 * DIM_, DIM_,
                   DIM_ / 32, acc);
    EPILOGUE_COORDS
    unsigned short* LT = LTb + (size_t)b * DD_ * S_;
    float psum[4] = {0.f, 0.f, 0.f, 0.f};
#pragma unroll
    for (int i = 0; i < 4; ++i)
#pragma unroll
        for (int j = 0; j < 4; ++j)
#pragma unroll
            for (int r = 0; r < 4; ++r) {
                float e = __expf(acc[i][j][r]);
                LT[(size_t)(m0 + mrow + i * 16 + q * 4 + r) * S_ +
                   n0 + ncol + j * 16 + col] = f2bf(e);
                psum[j] += e;
            }
    const int slice = (wave >> 1) * 4 + q;
#pragma unroll
    for (int j = 0; j < 4; ++j) csum[slice][ncol + j * 16 + col] = psum[j];
    __syncthreads();
    const int t = threadIdx.x;
    if (t < 128) {
        float v = 0.f;
#pragma unroll
        for (int k = 0; k < 8; ++k) v += csum[k][t];
        Lpart[((size_t)b * 8 + yd) * S_ + n0 + t] = v;
    }
}

// ---------------------------------------------------------------------------
// k_finalize: scale[b][s] = softplus(state[b][s]) / sum_tiles Lpart
// (scale parks in d_out's d_val region — fully overwritten by k_dvalW later)
// ---------------------------------------------------------------------------
__global__ __launch_bounds__(256) void k_finalize(const float* __restrict__ state,
                                                  const float* __restrict__ Lpart,
                                                  float* __restrict__ scale) {
    const int i = blockIdx.x * 256 + threadIdx.x;    // flat b*S+s
    const int b = i >> 12, s = i & (S_ - 1);
    float d = 0.f;
#pragma unroll
    for (int k = 0; k < 8; ++k) d += Lpart[((size_t)b * 8 + k) * S_ + s];
    const float st = state[i];
    const float sp = (st > 15.f) ? st : log1pf(__expf(st));
    scale[i] = sp / d;
}

// ---------------------------------------------------------------------------
// k_srcT: srcST[b][d'][s] = bf16( scale[b][s] * srcb[b][s][d'] )
// 64x64 tile transpose through LDS (stride-65 halfword padding).
// ---------------------------------------------------------------------------
__global__ __launch_bounds__(256) void k_srcT(const unsigned short* __restrict__ srcb,
                                              const float* __restrict__ scale,
                                              unsigned short* __restrict__ srcST) {
    __shared__ unsigned short Ts[64 * 65];
    const int s0 = blockIdx.x * 64, d0 = blockIdx.y * 64, b = blockIdx.z;
    const int t = threadIdx.x;
    {
        const int r = t >> 2, c0 = (t & 3) * 16;   // r = s-local, c = d'-local
        const unsigned short* g =
            srcb + (size_t)b * S_ * DIM_ + (size_t)(s0 + r) * DIM_ + d0 + c0;
        uint4 v0 = *(const uint4*)g;
        uint4 v1 = *(const uint4*)(g + 8);
        const unsigned short* e0 = (const unsigned short*)&v0;
        const unsigned short* e1 = (const unsigned short*)&v1;
        const float sc = scale[(size_t)b * S_ + s0 + r];
#pragma unroll
        for (int i = 0; i < 8; ++i) {
            Ts[r * 65 + c0 + i]     = f2bf(bf2f(e0[i]) * sc);
            Ts[r * 65 + c0 + 8 + i] = f2bf(bf2f(e1[i]) * sc);
        }
    }
    __syncthreads();
    {
        const int rr = t >> 2, c0 = (t & 3) * 16;  // rr = d'-local, c = s-local
        unsigned short tmp[16];
#pragma unroll
        for (int j = 0; j < 16; ++j) tmp[j] = Ts[(c0 + j) * 65 + rr];
        unsigned short* o =
            srcST + (size_t)b * DIM_ * S_ + (size_t)(d0 + rr) * S_ + s0 + c0;
        *(uint4*)o = *(const uint4*)tmp;
        *(uint4*)(o + 8) = *(const uint4*)(tmp + 8);
    }
}

// ---------------------------------------------------------------------------
// k_dstate: delta_state[b][dd] = sum_s LT[dd][s] * scale[b][s] * state[b][s]
// ---------------------------------------------------------------------------
__global__ __launch_bounds__(256) void k_dstate(const unsigned short* __restrict__ LT,
                                                const float* __restrict__ state,
                                                const float* __restrict__ scale,
                                                float* __restrict__ out) {
    const int b = blockIdx.y;
    const int dd = blockIdx.x * 4 + (threadIdx.x >> 6);
    const int lane = threadIdx.x & 63;
    const unsigned short* row = LT + (size_t)b * DD_ * S_ + (size_t)dd * S_;
    const float* st = state + (size_t)b * S_;
    const float* sc = scale + (size_t)b * S_;

    float acc = 0.f;
#pragma unroll
    for (int it = 0; it < S_ / 512; ++it) {
        const int s = it * 512 + lane * 8;
        uint4 v = *(const uint4*)(row + s);
        const unsigned short* e = (const unsigned short*)&v;
        float4 f0 = *(const float4*)(st + s);
        float4 f1 = *(const float4*)(st + s + 4);
        float4 c0 = *(const float4*)(sc + s);
        float4 c1 = *(const float4*)(sc + s + 4);
        acc += bf2f(e[0]) * f0.x * c0.x + bf2f(e[1]) * f0.y * c0.y +
               bf2f(e[2]) * f0.z * c0.z + bf2f(e[3]) * f0.w * c0.w +
               bf2f(e[4]) * f1.x * c1.x + bf2f(e[5]) * f1.y * c1.y +
               bf2f(e[6]) * f1.z * c1.z + bf2f(e[7]) * f1.w * c1.w;
    }
#pragma unroll
    for (int off = 32; off; off >>= 1) acc += __shfl_down(acc, off);
    if (lane == 0) out[(size_t)b * DD_ + dd] = acc;
}

// ---------------------------------------------------------------------------
// k_dU: partial[ks][b][dd][d'] = sum_{s slice} LT[dd][s]*srcST[d'][s], fp16
// split-K=4; XCD swizzle: each z=(b,ks) pinned to one XCD (3MB < 4MB L2).
// ---------------------------------------------------------------------------
__global__ __launch_bounds__(256) void k_dU(const unsigned short* __restrict__ LTb,
                                            const unsigned short* __restrict__ srcST,
                                            __half* __restrict__ Pp) {
    __shared__ unsigned short As[2 * 128 * 32];
    __shared__ unsigned short Bs[2 * 128 * 32];
    const int n = blockIdx.x;
    const int z = (n & 7) + 8 * (n >> 8);   // [0,32): (b,ks) -> XCD = n&7
    const int rem = (n >> 3) & 31;
    const int xe = rem >> 3;                // d'-tile [0,4), changes slowly
    const int yd = rem & 7;                 // dd-tile [0,8)
    const int b = z >> 2, ks = z & 3;
    const int n0 = xe * 128, m0 = yd * 128;
    ACC_INIT
    mainloop<0, 0>(As, Bs,
                   LTb + (size_t)b * DD_ * S_ + (size_t)m0 * S_ + ks * 1024, S_,
                   srcST + (size_t)b * DIM_ * S_ + (size_t)n0 * S_ + ks * 1024, S_,
                   1024 / 32, acc);
    EPILOGUE_COORDS
    __half* O = Pp + (size_t)ks * B_ * DD_ * DIM_ + (size_t)b * DD_ * DIM_;
#pragma unroll
    for (int i = 0; i < 4; ++i)
#pragma unroll
        for (int j = 0; j < 4; ++j)
#pragma unroll
            for (int r = 0; r < 4; ++r)
                O[(size_t)(m0 + mrow + i * 16 + q * 4 + r) * DIM_ +
                  n0 + ncol + j * 16 + col] = __float2half(acc[i][j][r]);
}

// ---------------------------------------------------------------------------
// k_reduceU: blocks [0,2048): U bf16 = sum of 4 fp16 partial slices
//            blocks [2048,2112): WvT[e][d] = bf16(Wv[d][e]) transpose
// ---------------------------------------------------------------------------
__global__ __launch_bounds__(256) void k_reduceU(const __half* __restrict__ Pp,
                                                 unsigned short* __restrict__ U,
                                                 const float* __restrict__ Wv,
                                                 unsigned short* __restrict__ WvT) {
    __shared__ float Ts[64 * 68];
    const int t = threadIdx.x;
    if (blockIdx.x < 2048) {
        const size_t idx = ((size_t)blockIdx.x * 256 + t) * 8;
        const size_t n = (size_t)B_ * DD_ * DIM_;
        float o[8] = {0.f, 0.f, 0.f, 0.f, 0.f, 0.f, 0.f, 0.f};
#pragma unroll
        for (int ks = 0; ks < 4; ++ks) {
            uint4 v = *(const uint4*)(Pp + (size_t)ks * n + idx);
            const __half* h = (const __half*)&v;
#pragma unroll
            for (int j = 0; j < 8; ++j) o[j] += __half2float(h[j]);
        }
        unsigned short tmp[8];
#pragma unroll
        for (int j = 0; j < 8; ++j) tmp[j] = f2bf(o[j]);
        *(uint4*)&U[idx] = *(const uint4*)tmp;
        return;
    }
    const int n2 = blockIdx.x - 2048;
    const int d0 = (n2 & 7) * 64, e0 = (n2 >> 3) * 64;
    {
        const int r = t >> 2, c0 = (t & 3) * 16;
        const float* g = Wv + (size_t)(d0 + r) * DIM_ + e0 + c0;
#pragma unroll
        for (int i = 0; i < 4; ++i)
            *(float4*)&Ts[r * 68 + c0 + i * 4] = *(const float4*)(g + i * 4);
    }
    __syncthreads();
    {
        const int rr = t >> 2, c0 = (t & 3) * 16;
        unsigned short tmp[16];
#pragma unroll
        for (int j = 0; j < 16; ++j) tmp[j] = f2bf(Ts[(c0 + j) * 68 + rr]);
        unsigned short* o = WvT + (size_t)(e0 + rr) * DIM_ + d0 + c0;
        *(uint4*)o = *(const uint4*)tmp;
        *(uint4*)(o + 8) = *(const uint4*)(tmp + 8);
    }
}

// ---------------------------------------------------------------------------
// k_dvalW: d_val[b*dd][e] = sum_d' U[b*dd][d'] * WvT[e][d']   (fp32 out)
// ---------------------------------------------------------------------------
__global__ __launch_bounds__(256) void k_dvalW(const unsigned short* __restrict__ U,
                                               const unsigned short* __restrict__ WvT,
                                               float* __restrict__ d_val) {
    __shared__ unsigned short As[2 * 128 * 32];
    __shared__ unsigned short Bs[2 * 128 * 32];
    const int n0 = blockIdx.x * 128, m0 = blockIdx.y * 128;
    ACC_INIT
    mainloop<0, 0>(As, Bs, U + (size_t)m0 * DIM_, DIM_,
                   WvT + (size_t)n0 * DIM_, DIM_, DIM_ / 32, acc);
    EPILOGUE_COORDS
#pragma unroll
    for (int i = 0; i < 4; ++i)
#pragma unroll
        for (int j = 0; j < 4; ++j)
#pragma unroll
            for (int r = 0; r < 4; ++r)
                d_val[(size_t)(m0 + mrow + i * 16 + q * 4 + r) * DIM_ +
                      n0 + ncol + j * 16 + col] = acc[i][j][r];
}

// ---------------------------------------------------------------------------
extern "C" void kernel_launch(void* const* d_in, const int* in_sizes, int n_in,
                              void* d_out, int out_size, void* d_ws, size_t ws_size,
                              hipStream_t stream) {
    const float* src   = (const float*)d_in[0];   // [B,S,DIM]
    const float* state = (const float*)d_in[1];   // [B,S]
    const float* dst   = (const float*)d_in[2];   // [B,D,DIM]
    const float* Wr    = (const float*)d_in[3];   // [DIM,DIM]
    const float* Wv    = (const float*)d_in[4];   // [DIM,DIM]

    // ws layout (128 MiB):
    //  A [0,32):  srcb bf16 (prep -> srcT); late: Pp fp16 4x8MiB (dU -> reduceU)
    //  B [32,96): LT bf16 (logitsT -> dU); late: U bf16 (8) + WvT (.5)
    //  C [96,128): early: DW(8) Lpart(1); late: srcST (32, srcT -> dU)
    //  scale parks in d_out's d_val region (overwritten by k_dvalW at the end)
    unsigned short* srcb = (unsigned short*)d_ws;
    __half* Pp = (__half*)d_ws;
    unsigned short* LT = srcb + (size_t)B_ * S_ * DIM_;
    unsigned short* U  = LT;                                   // overlays dead LT
    unsigned short* WvT = U + (size_t)B_ * DD_ * DIM_;
    unsigned short* C = LT + (size_t)B_ * DD_ * S_;
    unsigned short* DW = C;
    float* Lpart = (float*)(DW + (size_t)B_ * DD_ * DIM_);     // [B][8][S]
    unsigned short* srcST = C;                                 // overlays dead DW/Lpart

    float* d_state = (float*)d_out;               // [B, DD]
    float* d_val   = (float*)d_out + B_ * DD_;    // [B, DD, DIM]
    float* scale   = d_val;                       // park (dead before k_dvalW writes)

    k_prep<<<dim3(8192), 256, 0, stream>>>(src, srcb);
    k_dstWr<<<dim3(DIM_ / 128, (B_ * DD_) / 128), 256, 0, stream>>>(dst, Wr, DW);
    k_logitsT<<<dim3(2048), 256, 0, stream>>>(DW, srcb, LT, Lpart);
    k_finalize<<<dim3((B_ * S_) / 256), 256, 0, stream>>>(state, Lpart, scale);
    k_dstate<<<dim3(DD_ / 4, B_), 256, 0, stream>>>(LT, state, scale, d_state);
    k_srcT<<<dim3(S_ / 64, DIM_ / 64, B_), 256, 0, stream>>>(srcb, scale, srcST);
    k_dU<<<dim3(1024), 256, 0, stream>>>(LT, srcST, Pp);
    k_reduceU<<<dim3(2048 + 64), 256, 0, stream>>>(Pp, U, Wv, WvT);
    k_dvalW<<<dim3(DIM_ / 128, (B_ * DD_) / 128), 256, 0, stream>>>(U, WvT, d_val);
}

// Round 2
// 278.915 us; speedup vs baseline: 1.0890x; 1.0377x over previous
//
#include <hip/hip_runtime.h>
#include <hip/hip_fp16.h>

#define B_   8
#define S_   4096
#define DD_  1024   // dst nodes
#define DIM_ 512
#define SCALE 0.044194173824159216f  // 1/sqrt(512)

typedef __bf16 bf16x8 __attribute__((ext_vector_type(8)));
typedef float  floatx4 __attribute__((ext_vector_type(4)));

__device__ inline unsigned short f2bf(float f) {
    union { float f; unsigned int u; } v; v.f = f;
    unsigned int r = v.u + 0x7fffu + ((v.u >> 16) & 1u);  // RNE
    return (unsigned short)(r >> 16);
}
__device__ inline float bf2f(unsigned short h) {
    union { unsigned int u; float f; } v; v.u = ((unsigned int)h) << 16;
    return v.f;
}
__device__ inline uint4 cvt8(const float* __restrict__ g) {
    float4 f0 = *(const float4*)g;
    float4 f1 = *(const float4*)(g + 4);
    unsigned short tmp[8] = {f2bf(f0.x), f2bf(f0.y), f2bf(f0.z), f2bf(f0.w),
                             f2bf(f1.x), f2bf(f1.y), f2bf(f1.z), f2bf(f1.w)};
    return *(const uint4*)tmp;
}
// async global->LDS, 16B per lane; lds base must be wave-uniform
__device__ inline void async16(unsigned short* lds, const unsigned short* g) {
    __builtin_amdgcn_global_load_lds(
        (const __attribute__((address_space(1))) void*)g,
        (__attribute__((address_space(3))) void*)lds, 16, 0, 0);
}

__device__ inline void vwait8() { asm volatile("s_waitcnt vmcnt(8)" ::: "memory"); }
__device__ inline void vwait4() { asm volatile("s_waitcnt vmcnt(4)" ::: "memory"); }
__device__ inline void vwait0() { asm volatile("s_waitcnt vmcnt(0)" ::: "memory"); }
#define SBAR   __builtin_amdgcn_s_barrier()
#define SCHED0 __builtin_amdgcn_sched_barrier(0)

// ===========================================================================
// 256x256xK 8-phase mainloop (T3+T4+T2+T5), BK=64, 512 threads = 8 waves
// (2M x 4N), per-wave output 128x64 (acc[8][4]).
// LDS per operand: [2 buf][2 khalf][256 rows][32 cols] bf16 = 64 KiB; total
// 128 KiB -> 1 block/CU. Each K-tile = 4 phases (m-half x k-half quadrant,
// 16 MFMA each): {ds_read subtile; stage 1 future half; SBAR; setprio(1);
// MFMA; setprio(0); [counted vmcnt]; SBAR}. Staging is issued 5-6 phases
// before its deadline; vmcnt(8) at phase-2/4 ends keeps 12 loads in flight
// (never drained to 0 mid-loop). Tail peel: vmcnt 8 -> 4 -> 0.
// Swizzle: phys 16B slot = logical ^ ((row>>1)&3), applied as inverse perm
// on the GLOBAL source (LDS dest stays linear for global_load_lds) and as a
// per-lane-constant XOR on the ds_read address -> 2-way (free) conflicts.
// Per-tile hazard proof: a half written at phase p targets a region whose
// last reader finished before the barrier ending phase p-1 (kk0 regions are
// only read in phases 1-2, kk1 only in 3-4; stages go after those barriers).
// ===========================================================================
__device__ inline void mainloop256(unsigned short* As, unsigned short* Bs,
                                   const unsigned short* __restrict__ Ap, size_t lda,
                                   const unsigned short* __restrict__ Bp, size_t ldb,
                                   int nk, floatx4 (&acc)[8][4]) {
    const int t = threadIdx.x, lane = t & 63, w = t >> 6;
    const int wm = w >> 2, wn = w & 3;
    const int fr = lane & 15;
    const int swz  = (((lane >> 4) ^ ((fr >> 1) & 3)) << 3);   // read-side slot XOR
    const int csrc = (((t & 3) ^ ((t >> 3) & 3)) << 3);        // source-side inverse

    const unsigned short* gA = Ap + (size_t)(t >> 2) * lda + csrc;
    const unsigned short* gB = Bp + (size_t)(t >> 2) * ldb + csrc;
    unsigned short* ldsA = As + w * 512;   // wave-uniform; +lane*16B implicit
    unsigned short* ldsB = Bs + w * 512;

    auto stgA = [&](int buf, int kt, int kh) {
        const unsigned short* g = gA + (size_t)kt * 64 + kh * 32;
        async16(ldsA + buf * 16384 + kh * 8192,        g);
        async16(ldsA + buf * 16384 + kh * 8192 + 4096, g + (size_t)128 * lda);
    };
    auto stgB = [&](int buf, int kt, int kh) {
        const unsigned short* g = gB + (size_t)kt * 64 + kh * 32;
        async16(ldsB + buf * 16384 + kh * 8192,        g);
        async16(ldsB + buf * 16384 + kh * 8192 + 4096, g + (size_t)128 * ldb);
    };

    // prologue: tile0 all 4 halves + tile1 k0 halves (12 loads in flight)
    stgA(0, 0, 0); stgB(0, 0, 0); stgA(0, 0, 1); stgB(0, 0, 1);
    stgA(1, 1, 0); stgB(1, 1, 0);
    vwait8();                       // tile0 kk0 resident
    SCHED0;
    SBAR;

    const int arow = wm * 128 + fr, brow = wn * 64 + fr;
    for (int kt = 0; kt < nk; ++kt) {
        const int cur = kt & 1;
        const bool sA = kt + 1 < nk, sB = kt + 2 < nk;
        const int base = cur * 16384;
        bf16x8 a[4], b[4], a2[4];
        // ---- phase 1: mh0 kk0 ----
#pragma unroll
        for (int i = 0; i < 4; ++i)
            a[i] = *(const bf16x8*)&As[base + (arow + i * 16) * 32 + swz];
#pragma unroll
        for (int j = 0; j < 4; ++j)
            b[j] = *(const bf16x8*)&Bs[base + (brow + j * 16) * 32 + swz];
        if (sA) stgA(cur ^ 1, kt + 1, 1);
        SCHED0;
        SBAR;
        __builtin_amdgcn_s_setprio(1);
#pragma unroll
        for (int i = 0; i < 4; ++i)
#pragma unroll
            for (int j = 0; j < 4; ++j)
                acc[i][j] = __builtin_amdgcn_mfma_f32_16x16x32_bf16(a[i], b[j], acc[i][j], 0, 0, 0);
        __builtin_amdgcn_s_setprio(0);
        SBAR;
        // ---- phase 2: mh1 kk0 ----
#pragma unroll
        for (int i = 0; i < 4; ++i)
            a2[i] = *(const bf16x8*)&As[base + (arow + 64 + i * 16) * 32 + swz];
        if (sA) stgB(cur ^ 1, kt + 1, 1);
        SCHED0;
        SBAR;
        __builtin_amdgcn_s_setprio(1);
#pragma unroll
        for (int i = 0; i < 4; ++i)
#pragma unroll
            for (int j = 0; j < 4; ++j)
                acc[4 + i][j] = __builtin_amdgcn_mfma_f32_16x16x32_bf16(a2[i], b[j], acc[4 + i][j], 0, 0, 0);
        __builtin_amdgcn_s_setprio(0);
        if (sA) vwait8(); else vwait0();   // tile kt kk1 halves resident
        SBAR;
        // ---- phase 3: mh0 kk1 ----
#pragma unroll
        for (int i = 0; i < 4; ++i)
            a[i] = *(const bf16x8*)&As[base + 8192 + (arow + i * 16) * 32 + swz];
#pragma unroll
        for (int j = 0; j < 4; ++j)
            b[j] = *(const bf16x8*)&Bs[base + 8192 + (brow + j * 16) * 32 + swz];
        if (sB) stgA(cur, kt + 2, 0);
        SCHED0;
        SBAR;
        __builtin_amdgcn_s_setprio(1);
#pragma unroll
        for (int i = 0; i < 4; ++i)
#pragma unroll
            for (int j = 0; j < 4; ++j)
                acc[i][j] = __builtin_amdgcn_mfma_f32_16x16x32_bf16(a[i], b[j], acc[i][j], 0, 0, 0);
        __builtin_amdgcn_s_setprio(0);
        SBAR;
        // ---- phase 4: mh1 kk1 ----
#pragma unroll
        for (int i = 0; i < 4; ++i)
            a2[i] = *(const bf16x8*)&As[base + 8192 + (arow + 64 + i * 16) * 32 + swz];
        if (sB) stgB(cur, kt + 2, 0);
        SCHED0;
        SBAR;
        __builtin_amdgcn_s_setprio(1);
#pragma unroll
        for (int i = 0; i < 4; ++i)
#pragma unroll
            for (int j = 0; j < 4; ++j)
                acc[4 + i][j] = __builtin_amdgcn_mfma_f32_16x16x32_bf16(a2[i], b[j], acc[4 + i][j], 0, 0, 0);
        __builtin_amdgcn_s_setprio(0);
        if (sA) { if (sB) vwait8(); else vwait4(); }  // next tile kk0 resident
        SBAR;
    }
}

#define ACC_INIT8                                           \
    floatx4 acc[8][4];                                      \
    _Pragma("unroll") for (int i = 0; i < 8; ++i)           \
        _Pragma("unroll") for (int j = 0; j < 4; ++j)       \
            acc[i][j] = (floatx4){0.f, 0.f, 0.f, 0.f};

// ---------------------------------------------------------------------------
// legacy 128x128xBK=32 mainloop (kept for k_dstWr fp32-staging / k_dvalW)
// ---------------------------------------------------------------------------
template <int AF32, int BF32>
__device__ inline void mainloop(unsigned short* As, unsigned short* Bs,
                                const void* Ap, size_t lda,
                                const void* Bp, size_t ldb,
                                int kIters, floatx4 (&acc)[4][4]) {
    const int t = threadIdx.x, lane = t & 63, wave = t >> 6;
    const int rA = t >> 2;
    const int cA = ((t & 3) ^ ((t >> 3) & 3)) * 8;      // swizzled source col
    const int mrow = (wave >> 1) * 64, ncol = (wave & 1) * 64;
    const int fr = lane & 15, fk = (lane >> 4) * 8;
    const int swz = (((fk >> 3) ^ ((fr >> 1) & 3)) << 3); // physical k-offset

    const unsigned short* gA16 = nullptr; const float* gA32 = nullptr;
    const unsigned short* gB16 = nullptr; const float* gB32 = nullptr;
    if (AF32) gA32 = (const float*)Ap + (size_t)rA * lda + cA;
    else      gA16 = (const unsigned short*)Ap + (size_t)rA * lda + cA;
    if (BF32) gB32 = (const float*)Bp + (size_t)rA * ldb + cA;
    else      gB16 = (const unsigned short*)Bp + (size_t)rA * ldb + cA;

    unsigned short* ldsA = As + wave * 512;
    unsigned short* ldsB = Bs + wave * 512;

    auto stage = [&](int buf) {
        const int o = buf * 4096;
        if (AF32) {
            *(uint4*)&As[o + t * 8]        = cvt8(gA32);
            *(uint4*)&As[o + 2048 + t * 8] = cvt8(gA32 + 64 * lda);
            gA32 += 32;
        } else {
            async16(ldsA + o,        gA16);
            async16(ldsA + o + 2048, gA16 + 64 * lda);
            gA16 += 32;
        }
        if (BF32) {
            *(uint4*)&Bs[o + t * 8]        = cvt8(gB32);
            *(uint4*)&Bs[o + 2048 + t * 8] = cvt8(gB32 + 64 * ldb);
            gB32 += 32;
        } else {
            async16(ldsB + o,        gB16);
            async16(ldsB + o + 2048, gB16 + 64 * ldb);
            gB16 += 32;
        }
    };

    stage(0);
    __syncthreads();
    for (int kt = 0; kt < kIters; ++kt) {
        if (kt + 1 < kIters) stage((kt + 1) & 1);
        const int cur = (kt & 1) * 4096;
        bf16x8 af[4], bfr[4];
#pragma unroll
        for (int i = 0; i < 4; ++i)
            af[i] = *(const bf16x8*)&As[cur + (mrow + i * 16 + fr) * 32 + swz];
#pragma unroll
        for (int j = 0; j < 4; ++j)
            bfr[j] = *(const bf16x8*)&Bs[cur + (ncol + j * 16 + fr) * 32 + swz];
#pragma unroll
        for (int i = 0; i < 4; ++i)
#pragma unroll
            for (int j = 0; j < 4; ++j)
                acc[i][j] = __builtin_amdgcn_mfma_f32_16x16x32_bf16(af[i], bfr[j],
                                                                    acc[i][j], 0, 0, 0);
        __syncthreads();
    }
}

#define EPILOGUE_COORDS                                     \
    const int lane = threadIdx.x & 63, wave = threadIdx.x >> 6; \
    const int mrow = (wave >> 1) * 64, ncol = (wave & 1) * 64;  \
    const int col = lane & 15, q = lane >> 4;

#define ACC_INIT                                            \
    floatx4 acc[4][4];                                      \
    _Pragma("unroll") for (int i = 0; i < 4; ++i)           \
        _Pragma("unroll") for (int j = 0; j < 4; ++j)       \
            acc[i][j] = (floatx4){0.f, 0.f, 0.f, 0.f};

// ---------------------------------------------------------------------------
// k_prep: srcb = bf16(src)
// ---------------------------------------------------------------------------
__global__ __launch_bounds__(256) void k_prep(const float* __restrict__ src,
                                              unsigned short* __restrict__ srcb) {
    const size_t idx = ((size_t)blockIdx.x * 256 + threadIdx.x) * 8;
    *(uint4*)&srcb[idx] = cvt8(src + idx);
}

// ---------------------------------------------------------------------------
// k_dstWr: DW[b*dd][d] = SCALE * sum_e dst[b*dd][e] * Wr[d][e]   (128² loop)
// ---------------------------------------------------------------------------
__global__ __launch_bounds__(256) void k_dstWr(const float* __restrict__ dst,
                                               const float* __restrict__ Wr,
                                               unsigned short* __restrict__ DW) {
    __shared__ unsigned short As[2 * 128 * 32];
    __shared__ unsigned short Bs[2 * 128 * 32];
    const int n0 = blockIdx.x * 128, m0 = blockIdx.y * 128;
    ACC_INIT
    mainloop<1, 1>(As, Bs, dst + (size_t)m0 * DIM_, DIM_,
                   Wr + (size_t)n0 * DIM_, DIM_, DIM_ / 32, acc);
    EPILOGUE_COORDS
#pragma unroll
    for (int i = 0; i < 4; ++i)
#pragma unroll
        for (int j = 0; j < 4; ++j)
#pragma unroll
            for (int r = 0; r < 4; ++r)
                DW[(size_t)(m0 + mrow + i * 16 + q * 4 + r) * DIM_ +
                   n0 + ncol + j * 16 + col] = f2bf(acc[i][j][r] * SCALE);
}

// ---------------------------------------------------------------------------
// k_logitsT: LT[dd][s] = exp(DW[dd][:] . srcb[s][:]) -> bf16  (per batch)
// 256² 8-phase loop. XCD: b = n&7; s-tile slow. Column sums -> Lpart [B][4][S].
// ---------------------------------------------------------------------------
__global__ __launch_bounds__(512) void k_logitsT(const unsigned short* __restrict__ DW,
                                                 const unsigned short* __restrict__ srcb,
                                                 unsigned short* __restrict__ LTb,
                                                 float* __restrict__ Lpart) {
    __shared__ __align__(16) unsigned short As[32768];
    __shared__ __align__(16) unsigned short Bs[32768];
    const int n = blockIdx.x;
    const int b = n & 7;          // -> XCD
    const int rem = n >> 3;       // [0,64)
    const int xs = rem >> 2;      // s-tile [0,16), slow (B L2-hot)
    const int yd = rem & 3;       // dd-tile [0,4)
    const int n0 = xs * 256, m0 = yd * 256;
    ACC_INIT8
    mainloop256(As, Bs,
                DW + (size_t)b * DD_ * DIM_ + (size_t)m0 * DIM_, DIM_,
                srcb + (size_t)b * S_ * DIM_ + (size_t)n0 * DIM_, DIM_,
                DIM_ / 64, acc);
    const int t = threadIdx.x, lane = t & 63, w = t >> 6;
    const int wm = w >> 2, wn = w & 3;
    const int c16 = lane & 15, q = lane >> 4;
    const int row0 = m0 + wm * 128, col0 = n0 + wn * 64;
    unsigned short* LT = LTb + (size_t)b * DD_ * S_;
    float psum[4] = {0.f, 0.f, 0.f, 0.f};
#pragma unroll
    for (int i = 0; i < 8; ++i)
#pragma unroll
        for (int j = 0; j < 4; ++j)
#pragma unroll
            for (int r = 0; r < 4; ++r) {
                float e = __expf(acc[i][j][r]);
                LT[(size_t)(row0 + i * 16 + q * 4 + r) * S_ +
                   col0 + j * 16 + c16] = f2bf(e);
                psum[j] += e;
            }
    float* csum = (float*)As;     // [8][256] overlay (buffers dead)
    const int slice = wm * 4 + q;
#pragma unroll
    for (int j = 0; j < 4; ++j)
        csum[slice * 256 + wn * 64 + j * 16 + c16] = psum[j];
    __syncthreads();
    if (t < 256) {
        float v = 0.f;
#pragma unroll
        for (int k = 0; k < 8; ++k) v += csum[k * 256 + t];
        Lpart[((size_t)b * 4 + yd) * S_ + n0 + t] = v;
    }
}

// ---------------------------------------------------------------------------
// k_finalize: scale[b][s] = softplus(state[b][s]) / sum_tiles Lpart (4 slices)
// ---------------------------------------------------------------------------
__global__ __launch_bounds__(256) void k_finalize(const float* __restrict__ state,
                                                  const float* __restrict__ Lpart,
                                                  float* __restrict__ scale) {
    const int i = blockIdx.x * 256 + threadIdx.x;    // flat b*S+s
    const int b = i >> 12, s = i & (S_ - 1);
    float d = 0.f;
#pragma unroll
    for (int k = 0; k < 4; ++k) d += Lpart[((size_t)b * 4 + k) * S_ + s];
    const float st = state[i];
    const float sp = (st > 15.f) ? st : log1pf(__expf(st));
    scale[i] = sp / d;
}

// ---------------------------------------------------------------------------
// k_srcT: srcST[b][d'][s] = bf16( scale[b][s] * srcb[b][s][d'] )
// ---------------------------------------------------------------------------
__global__ __launch_bounds__(256) void k_srcT(const unsigned short* __restrict__ srcb,
                                              const float* __restrict__ scale,
                                              unsigned short* __restrict__ srcST) {
    __shared__ unsigned short Ts[64 * 65];
    const int s0 = blockIdx.x * 64, d0 = blockIdx.y * 64, b = blockIdx.z;
    const int t = threadIdx.x;
    {
        const int r = t >> 2, c0 = (t & 3) * 16;   // r = s-local, c = d'-local
        const unsigned short* g =
            srcb + (size_t)b * S_ * DIM_ + (size_t)(s0 + r) * DIM_ + d0 + c0;
        uint4 v0 = *(const uint4*)g;
        uint4 v1 = *(const uint4*)(g + 8);
        const unsigned short* e0 = (const unsigned short*)&v0;
        const unsigned short* e1 = (const unsigned short*)&v1;
        const float sc = scale[(size_t)b * S_ + s0 + r];
#pragma unroll
        for (int i = 0; i < 8; ++i) {
            Ts[r * 65 + c0 + i]     = f2bf(bf2f(e0[i]) * sc);
            Ts[r * 65 + c0 + 8 + i] = f2bf(bf2f(e1[i]) * sc);
        }
    }
    __syncthreads();
    {
        const int rr = t >> 2, c0 = (t & 3) * 16;  // rr = d'-local, c = s-local
        unsigned short tmp[16];
#pragma unroll
        for (int j = 0; j < 16; ++j) tmp[j] = Ts[(c0 + j) * 65 + rr];
        unsigned short* o =
            srcST + (size_t)b * DIM_ * S_ + (size_t)(d0 + rr) * S_ + s0 + c0;
        *(uint4*)o = *(const uint4*)tmp;
        *(uint4*)(o + 8) = *(const uint4*)(tmp + 8);
    }
}

// ---------------------------------------------------------------------------
// k_dstate: delta_state[b][dd] = sum_s LT[dd][s] * scale[b][s] * state[b][s]
// ---------------------------------------------------------------------------
__global__ __launch_bounds__(256) void k_dstate(const unsigned short* __restrict__ LT,
                                                const float* __restrict__ state,
                                                const float* __restrict__ scale,
                                                float* __restrict__ out) {
    const int b = blockIdx.y;
    const int dd = blockIdx.x * 4 + (threadIdx.x >> 6);
    const int lane = threadIdx.x & 63;
    const unsigned short* row = LT + (size_t)b * DD_ * S_ + (size_t)dd * S_;
    const float* st = state + (size_t)b * S_;
    const float* sc = scale + (size_t)b * S_;

    float acc = 0.f;
#pragma unroll
    for (int it = 0; it < S_ / 512; ++it) {
        const int s = it * 512 + lane * 8;
        uint4 v = *(const uint4*)(row + s);
        const unsigned short* e = (const unsigned short*)&v;
        float4 f0 = *(const float4*)(st + s);
        float4 f1 = *(const float4*)(st + s + 4);
        float4 c0 = *(const float4*)(sc + s);
        float4 c1 = *(const float4*)(sc + s + 4);
        acc += bf2f(e[0]) * f0.x * c0.x + bf2f(e[1]) * f0.y * c0.y +
               bf2f(e[2]) * f0.z * c0.z + bf2f(e[3]) * f0.w * c0.w +
               bf2f(e[4]) * f1.x * c1.x + bf2f(e[5]) * f1.y * c1.y +
               bf2f(e[6]) * f1.z * c1.z + bf2f(e[7]) * f1.w * c1.w;
    }
#pragma unroll
    for (int off = 32; off; off >>= 1) acc += __shfl_down(acc, off);
    if (lane == 0) out[(size_t)b * DD_ + dd] = acc;
}

// ---------------------------------------------------------------------------
// k_dU: partial[ks][b][dd][d'] = sum_{s slice} LT[dd][s]*srcST[d'][s], fp16
// 256² 8-phase loop, split-K=4; all 8 tiles of one (b,ks) pinned to one XCD.
// ---------------------------------------------------------------------------
__global__ __launch_bounds__(512) void k_dU(const unsigned short* __restrict__ LTb,
                                            const unsigned short* __restrict__ srcST,
                                            __half* __restrict__ Pp) {
    __shared__ __align__(16) unsigned short As[32768];
    __shared__ __align__(16) unsigned short Bs[32768];
    const int n = blockIdx.x;                 // [0,256)
    const int qn = n >> 3;                    // [0,32)
    const int tile = qn & 7, zhi = qn >> 3;   // tile [0,8), zhi [0,4)
    const int z = (n & 7) + 8 * zhi;          // (b,ks) [0,32); XCD = n&7 = z&7
    const int b = z >> 2, ks = z & 3;
    const int xe = tile >> 2;                 // d'-tile [0,2)
    const int yd = tile & 3;                  // dd-tile [0,4)
    const int n0 = xe * 256, m0 = yd * 256;
    ACC_INIT8
    mainloop256(As, Bs,
                LTb + (size_t)b * DD_ * S_ + (size_t)m0 * S_ + ks * 1024, S_,
                srcST + (size_t)b * DIM_ * S_ + (size_t)n0 * S_ + ks * 1024, S_,
                1024 / 64, acc);
    const int t = threadIdx.x, lane = t & 63, w = t >> 6;
    const int wm = w >> 2, wn = w & 3;
    const int c16 = lane & 15, q = lane >> 4;
    const int row0 = m0 + wm * 128, col0 = n0 + wn * 64;
    __half* O = Pp + (size_t)ks * B_ * DD_ * DIM_ + (size_t)b * DD_ * DIM_;
#pragma unroll
    for (int i = 0; i < 8; ++i)
#pragma unroll
        for (int j = 0; j < 4; ++j)
#pragma unroll
            for (int r = 0; r < 4; ++r)
                O[(size_t)(row0 + i * 16 + q * 4 + r) * DIM_ +
                  col0 + j * 16 + c16] = __float2half(acc[i][j][r]);
}

// ---------------------------------------------------------------------------
// k_reduceU: blocks [0,2048): U bf16 = sum of 4 fp16 partial slices
//            blocks [2048,2112): WvT[e][d] = bf16(Wv[d][e]) transpose
// ---------------------------------------------------------------------------
__global__ __launch_bounds__(256) void k_reduceU(const __half* __restrict__ Pp,
                                                 unsigned short* __restrict__ U,
                                                 const float* __restrict__ Wv,
                                                 unsigned short* __restrict__ WvT) {
    __shared__ float Ts[64 * 68];
    const int t = threadIdx.x;
    if (blockIdx.x < 2048) {
        const size_t idx = ((size_t)blockIdx.x * 256 + t) * 8;
        const size_t n = (size_t)B_ * DD_ * DIM_;
        float o[8] = {0.f, 0.f, 0.f, 0.f, 0.f, 0.f, 0.f, 0.f};
#pragma unroll
        for (int ks = 0; ks < 4; ++ks) {
            uint4 v = *(const uint4*)(Pp + (size_t)ks * n + idx);
            const __half* h = (const __half*)&v;
#pragma unroll
            for (int j = 0; j < 8; ++j) o[j] += __half2float(h[j]);
        }
        unsigned short tmp[8];
#pragma unroll
        for (int j = 0; j < 8; ++j) tmp[j] = f2bf(o[j]);
        *(uint4*)&U[idx] = *(const uint4*)tmp;
        return;
    }
    const int n2 = blockIdx.x - 2048;
    const int d0 = (n2 & 7) * 64, e0 = (n2 >> 3) * 64;
    {
        const int r = t >> 2, c0 = (t & 3) * 16;
        const float* g = Wv + (size_t)(d0 + r) * DIM_ + e0 + c0;
#pragma unroll
        for (int i = 0; i < 4; ++i)
            *(float4*)&Ts[r * 68 + c0 + i * 4] = *(const float4*)(g + i * 4);
    }
    __syncthreads();
    {
        const int rr = t >> 2, c0 = (t & 3) * 16;
        unsigned short tmp[16];
#pragma unroll
        for (int j = 0; j < 16; ++j) tmp[j] = f2bf(Ts[(c0 + j) * 68 + rr]);
        unsigned short* o = WvT + (size_t)(e0 + rr) * DIM_ + d0 + c0;
        *(uint4*)o = *(const uint4*)tmp;
        *(uint4*)(o + 8) = *(const uint4*)(tmp + 8);
    }
}

// ---------------------------------------------------------------------------
// k_dvalW: d_val[b*dd][e] = sum_d' U[b*dd][d'] * WvT[e][d']   (fp32 out, 128²)
// ---------------------------------------------------------------------------
__global__ __launch_bounds__(256) void k_dvalW(const unsigned short* __restrict__ U,
                                               const unsigned short* __restrict__ WvT,
                                               float* __restrict__ d_val) {
    __shared__ unsigned short As[2 * 128 * 32];
    __shared__ unsigned short Bs[2 * 128 * 32];
    const int n0 = blockIdx.x * 128, m0 = blockIdx.y * 128;
    ACC_INIT
    mainloop<0, 0>(As, Bs, U + (size_t)m0 * DIM_, DIM_,
                   WvT + (size_t)n0 * DIM_, DIM_, DIM_ / 32, acc);
    EPILOGUE_COORDS
#pragma unroll
    for (int i = 0; i < 4; ++i)
#pragma unroll
        for (int j = 0; j < 4; ++j)
#pragma unroll
            for (int r = 0; r < 4; ++r)
                d_val[(size_t)(m0 + mrow + i * 16 + q * 4 + r) * DIM_ +
                      n0 + ncol + j * 16 + col] = acc[i][j][r];
}

// ---------------------------------------------------------------------------
extern "C" void kernel_launch(void* const* d_in, const int* in_sizes, int n_in,
                              void* d_out, int out_size, void* d_ws, size_t ws_size,
                              hipStream_t stream) {
    const float* src   = (const float*)d_in[0];   // [B,S,DIM]
    const float* state = (const float*)d_in[1];   // [B,S]
    const float* dst   = (const float*)d_in[2];   // [B,D,DIM]
    const float* Wr    = (const float*)d_in[3];   // [DIM,DIM]
    const float* Wv    = (const float*)d_in[4];   // [DIM,DIM]

    // ws layout (128 MiB):
    //  A [0,32):  srcb bf16 (prep -> srcT); late: Pp fp16 4x8MiB (dU -> reduceU)
    //  B [32,96): LT bf16 (logitsT -> dU); late: U bf16 (8) + WvT (.5)
    //  C [96,128): early: DW(8) Lpart(.5); late: srcST (32, srcT -> dU)
    //  scale parks in d_out's d_val region (overwritten by k_dvalW at the end)
    unsigned short* srcb = (unsigned short*)d_ws;
    __half* Pp = (__half*)d_ws;
    unsigned short* LT = srcb + (size_t)B_ * S_ * DIM_;
    unsigned short* U  = LT;                                   // overlays dead LT
    unsigned short* WvT = U + (size_t)B_ * DD_ * DIM_;
    unsigned short* C = LT + (size_t)B_ * DD_ * S_;
    unsigned short* DW = C;
    float* Lpart = (float*)(DW + (size_t)B_ * DD_ * DIM_);     // [B][4][S]
    unsigned short* srcST = C;                                 // overlays dead DW/Lpart

    float* d_state = (float*)d_out;               // [B, DD]
    float* d_val   = (float*)d_out + B_ * DD_;    // [B, DD, DIM]
    float* scale   = d_val;                       // park (dead before k_dvalW writes)

    k_prep<<<dim3(8192), 256, 0, stream>>>(src, srcb);
    k_dstWr<<<dim3(DIM_ / 128, (B_ * DD_) / 128), 256, 0, stream>>>(dst, Wr, DW);
    k_logitsT<<<dim3(512), 512, 0, stream>>>(DW, srcb, LT, Lpart);
    k_finalize<<<dim3((B_ * S_) / 256), 256, 0, stream>>>(state, Lpart, scale);
    k_dstate<<<dim3(DD_ / 4, B_), 256, 0, stream>>>(LT, state, scale, d_state);
    k_srcT<<<dim3(S_ / 64, DIM_ / 64, B_), 256, 0, stream>>>(srcb, scale, srcST);
    k_dU<<<dim3(256), 512, 0, stream>>>(LT, srcST, Pp);
    k_reduceU<<<dim3(2048 + 64), 256, 0, stream>>>(Pp, U, Wv, WvT);
    k_dvalW<<<dim3(DIM_ / 128, (B_ * DD_) / 128), 256, 0, stream>>>(U, WvT, d_val);
}

// Round 4
// 272.256 us; speedup vs baseline: 1.1157x; 1.0245x over previous
//
#include <hip/hip_runtime.h>
#include <hip/hip_fp16.h>

#define B_   8
#define S_   4096
#define DD_  1024   // dst nodes
#define DIM_ 512
#define SCALE 0.044194173824159216f  // 1/sqrt(512)

typedef __bf16 bf16x8 __attribute__((ext_vector_type(8)));
typedef float  floatx4 __attribute__((ext_vector_type(4)));

__device__ inline unsigned short f2bf(float f) {
    union { float f; unsigned int u; } v; v.f = f;
    unsigned int r = v.u + 0x7fffu + ((v.u >> 16) & 1u);  // RNE
    return (unsigned short)(r >> 16);
}
__device__ inline float bf2f(unsigned short h) {
    union { unsigned int u; float f; } v; v.u = ((unsigned int)h) << 16;
    return v.f;
}
__device__ inline uint4 cvt8(const float* __restrict__ g) {
    float4 f0 = *(const float4*)g;
    float4 f1 = *(const float4*)(g + 4);
    unsigned short tmp[8] = {f2bf(f0.x), f2bf(f0.y), f2bf(f0.z), f2bf(f0.w),
                             f2bf(f1.x), f2bf(f1.y), f2bf(f1.z), f2bf(f1.w)};
    return *(const uint4*)tmp;
}
// async global->LDS, 16B per lane; lds base must be wave-uniform
__device__ inline void async16(unsigned short* lds, const unsigned short* g) {
    __builtin_amdgcn_global_load_lds(
        (const __attribute__((address_space(1))) void*)g,
        (__attribute__((address_space(3))) void*)lds, 16, 0, 0);
}

template <int N> __device__ inline void vwait() {
    if constexpr (N == 0)      asm volatile("s_waitcnt vmcnt(0)" ::: "memory");
    else if constexpr (N == 4) asm volatile("s_waitcnt vmcnt(4)" ::: "memory");
    else if constexpr (N == 6) asm volatile("s_waitcnt vmcnt(6)" ::: "memory");
    else                       asm volatile("s_waitcnt vmcnt(8)" ::: "memory");
}
#define SBAR   __builtin_amdgcn_s_barrier()
#define SCHED0 __builtin_amdgcn_sched_barrier(0)

// ===========================================================================
// 256x256xK fully-pipelined mainloop, BK=64, 512 threads = 8 waves (2M x 4N),
// per-wave output 128x64 (acc[8][4]).
// LDS per operand: [2 buf][2 khalf][256][32] bf16 = 64 KiB; 128 KiB total.
// 4 phases/K-tile, ONE barrier per phase. Every phase's ds_reads are issued
// one phase EARLY, inside the previous phase's MFMA cluster, so the LDS pipe
// runs under the MFMA pipe (R2's version serialized them -> 27% MfmaUtil).
// Register pipeline: ph1 MFMA(a0,b0 kk0mh0) reads a1(kk0mh1); ph2 MFMA(a1,b0)
// reads a2,b2(kk1mh0+B); ph3 MFMA(a2,b2) reads a3(kk1mh1); ph4 MFMA(a3,b2)
// reads next-tile a0,b0.
// Counted vmcnt, shifted one phase early so prefetched reads are legal:
//   end-ph1: vmcnt(6) -> this tile's kk1 resident (read in ph2's cluster)
//   end-ph3: vmcnt(6|4) -> next tile's kk0 resident (read in ph4's cluster)
//   last tile: vmcnt(0) at end-ph1 (full drain, epilogue-safe).
// Stage issue points (A(kt+1,k1)@ph1, B(kt+1,k1)@ph2, A(kt+2,k0)@ph3,
// B(kt+2,k0)@ph4) are each >=1 barrier AFTER the last MFMA-consumption of
// their target region (WAR ledger verified per phase); cross-wave RAW is
// (own vwait) -> barrier -> read. 12 loads in flight steady state.
// Swizzle: phys 16B slot = logical ^ ((row>>1)&3); inverse perm on the
// GLOBAL source (LDS dest linear for global_load_lds), per-lane-constant
// XOR on ds_read. MFMA K-order identical across versions -> bit-identical.
// ===========================================================================
__device__ inline void mainloop256(unsigned short* As, unsigned short* Bs,
                                   const unsigned short* __restrict__ Ap, size_t lda,
                                   const unsigned short* __restrict__ Bp, size_t ldb,
                                   int nk, floatx4 (&acc)[8][4]) {
    const int t = threadIdx.x, lane = t & 63, w = t >> 6;
    const int wm = w >> 2, wn = w & 3;
    const int fr = lane & 15;
    const int swz  = (((lane >> 4) ^ ((fr >> 1) & 3)) << 3);   // read-side slot XOR
    const int csrc = (((t & 3) ^ ((t >> 3) & 3)) << 3);        // source-side inverse

    const unsigned short* gA = Ap + (size_t)(t >> 2) * lda + csrc;
    const unsigned short* gB = Bp + (size_t)(t >> 2) * ldb + csrc;
    unsigned short* ldsA = As + w * 512;   // wave-uniform; +lane*16B implicit
    unsigned short* ldsB = Bs + w * 512;

    auto stgA = [&](int buf, int kt, int kh) {
        const unsigned short* g = gA + (size_t)kt * 64 + kh * 32;
        async16(ldsA + buf * 16384 + kh * 8192,        g);
        async16(ldsA + buf * 16384 + kh * 8192 + 4096, g + (size_t)128 * lda);
    };
    auto stgB = [&](int buf, int kt, int kh) {
        const unsigned short* g = gB + (size_t)kt * 64 + kh * 32;
        async16(ldsB + buf * 16384 + kh * 8192,        g);
        async16(ldsB + buf * 16384 + kh * 8192 + 4096, g + (size_t)128 * ldb);
    };

    // prologue: tile0 (kk0,kk1) + tile1 kk0 = 12 loads in flight
    stgA(0, 0, 0); stgB(0, 0, 0); stgA(0, 0, 1); stgB(0, 0, 1);
    stgA(1, 1, 0); stgB(1, 1, 0);
    vwait<8>();                     // tile0 kk0 resident
    SCHED0;
    SBAR;

    const int arow = wm * 128 + fr, brow = wn * 64 + fr;
    bf16x8 a0[4], b0[4], a1[4], a2[4], b2[4], a3[4];
#pragma unroll
    for (int i = 0; i < 4; ++i) a0[i] = *(const bf16x8*)&As[(arow + i * 16) * 32 + swz];
#pragma unroll
    for (int j = 0; j < 4; ++j) b0[j] = *(const bf16x8*)&Bs[(brow + j * 16) * 32 + swz];

    for (int kt = 0; kt < nk; ++kt) {
        const int cur = kt & 1, base = cur * 16384;
        const bool sA = kt + 1 < nk, sB = kt + 2 < nk;
        // ---- ph1: MFMA mh0/kk0; prefetch a1 (mh1/kk0); stage A(kt+1,k1) ----
        if (sA) stgA(cur ^ 1, kt + 1, 1);
        SCHED0;
        __builtin_amdgcn_s_setprio(1);
#pragma unroll
        for (int i = 0; i < 4; ++i)
            a1[i] = *(const bf16x8*)&As[base + (arow + 64 + i * 16) * 32 + swz];
#pragma unroll
        for (int i = 0; i < 4; ++i)
#pragma unroll
            for (int j = 0; j < 4; ++j)
                acc[i][j] = __builtin_amdgcn_mfma_f32_16x16x32_bf16(a0[i], b0[j], acc[i][j], 0, 0, 0);
        __builtin_amdgcn_s_setprio(0);
        if (sA) vwait<6>(); else vwait<0>();   // this tile's kk1 resident
        SBAR;
        // ---- ph2: MFMA mh1/kk0; prefetch a2,b2 (kk1); stage B(kt+1,k1) ----
        if (sA) stgB(cur ^ 1, kt + 1, 1);
        SCHED0;
        __builtin_amdgcn_s_setprio(1);
#pragma unroll
        for (int i = 0; i < 4; ++i)
            a2[i] = *(const bf16x8*)&As[base + 8192 + (arow + i * 16) * 32 + swz];
#pragma unroll
        for (int j = 0; j < 4; ++j)
            b2[j] = *(const bf16x8*)&Bs[base + 8192 + (brow + j * 16) * 32 + swz];
#pragma unroll
        for (int i = 0; i < 4; ++i)
#pragma unroll
            for (int j = 0; j < 4; ++j)
                acc[4 + i][j] = __builtin_amdgcn_mfma_f32_16x16x32_bf16(a1[i], b0[j], acc[4 + i][j], 0, 0, 0);
        __builtin_amdgcn_s_setprio(0);
        SBAR;
        // ---- ph3: MFMA mh0/kk1; prefetch a3 (mh1/kk1); stage A(kt+2,k0) ----
        if (sB) stgA(cur, kt + 2, 0);
        SCHED0;
        __builtin_amdgcn_s_setprio(1);
#pragma unroll
        for (int i = 0; i < 4; ++i)
            a3[i] = *(const bf16x8*)&As[base + 8192 + (arow + 64 + i * 16) * 32 + swz];
#pragma unroll
        for (int i = 0; i < 4; ++i)
#pragma unroll
            for (int j = 0; j < 4; ++j)
                acc[i][j] = __builtin_amdgcn_mfma_f32_16x16x32_bf16(a2[i], b2[j], acc[i][j], 0, 0, 0);
        __builtin_amdgcn_s_setprio(0);
        if (sA) { if (sB) vwait<6>(); else vwait<4>(); }  // next tile kk0 resident
        SBAR;
        // ---- ph4: MFMA mh1/kk1; prefetch next a0,b0 (kk0); stage B(kt+2,k0) ----
        if (sB) stgB(cur, kt + 2, 0);
        SCHED0;
        __builtin_amdgcn_s_setprio(1);
        if (sA) {
            const int nb = (cur ^ 1) * 16384;
#pragma unroll
            for (int i = 0; i < 4; ++i)
                a0[i] = *(const bf16x8*)&As[nb + (arow + i * 16) * 32 + swz];
#pragma unroll
            for (int j = 0; j < 4; ++j)
                b0[j] = *(const bf16x8*)&Bs[nb + (brow + j * 16) * 32 + swz];
        }
#pragma unroll
        for (int i = 0; i < 4; ++i)
#pragma unroll
            for (int j = 0; j < 4; ++j)
                acc[4 + i][j] = __builtin_amdgcn_mfma_f32_16x16x32_bf16(a3[i], b2[j], acc[4 + i][j], 0, 0, 0);
        __builtin_amdgcn_s_setprio(0);
        SBAR;
    }
}

#define ACC_INIT8                                           \
    floatx4 acc[8][4];                                      \
    _Pragma("unroll") for (int i = 0; i < 8; ++i)           \
        _Pragma("unroll") for (int j = 0; j < 4; ++j)       \
            acc[i][j] = (floatx4){0.f, 0.f, 0.f, 0.f};

// ---------------------------------------------------------------------------
// legacy 128x128xBK=32 mainloop (kept for k_dstWr fp32-staging / k_dvalW)
// ---------------------------------------------------------------------------
template <int AF32, int BF32>
__device__ inline void mainloop(unsigned short* As, unsigned short* Bs,
                                const void* Ap, size_t lda,
                                const void* Bp, size_t ldb,
                                int kIters, floatx4 (&acc)[4][4]) {
    const int t = threadIdx.x, lane = t & 63, wave = t >> 6;
    const int rA = t >> 2;
    const int cA = ((t & 3) ^ ((t >> 3) & 3)) * 8;      // swizzled source col
    const int mrow = (wave >> 1) * 64, ncol = (wave & 1) * 64;
    const int fr = lane & 15, fk = (lane >> 4) * 8;
    const int swz = (((fk >> 3) ^ ((fr >> 1) & 3)) << 3); // physical k-offset

    const unsigned short* gA16 = nullptr; const float* gA32 = nullptr;
    const unsigned short* gB16 = nullptr; const float* gB32 = nullptr;
    if (AF32) gA32 = (const float*)Ap + (size_t)rA * lda + cA;
    else      gA16 = (const unsigned short*)Ap + (size_t)rA * lda + cA;
    if (BF32) gB32 = (const float*)Bp + (size_t)rA * ldb + cA;
    else      gB16 = (const unsigned short*)Bp + (size_t)rA * ldb + cA;

    unsigned short* ldsA = As + wave * 512;
    unsigned short* ldsB = Bs + wave * 512;

    auto stage = [&](int buf) {
        const int o = buf * 4096;
        if (AF32) {
            *(uint4*)&As[o + t * 8]        = cvt8(gA32);
            *(uint4*)&As[o + 2048 + t * 8] = cvt8(gA32 + 64 * lda);
            gA32 += 32;
        } else {
            async16(ldsA + o,        gA16);
            async16(ldsA + o + 2048, gA16 + 64 * lda);
            gA16 += 32;
        }
        if (BF32) {
            *(uint4*)&Bs[o + t * 8]        = cvt8(gB32);
            *(uint4*)&Bs[o + 2048 + t * 8] = cvt8(gB32 + 64 * ldb);
            gB32 += 32;
        } else {
            async16(ldsB + o,        gB16);
            async16(ldsB + o + 2048, gB16 + 64 * ldb);
            gB16 += 32;
        }
    };

    stage(0);
    __syncthreads();
    for (int kt = 0; kt < kIters; ++kt) {
        if (kt + 1 < kIters) stage((kt + 1) & 1);
        const int cur = (kt & 1) * 4096;
        bf16x8 af[4], bfr[4];
#pragma unroll
        for (int i = 0; i < 4; ++i)
            af[i] = *(const bf16x8*)&As[cur + (mrow + i * 16 + fr) * 32 + swz];
#pragma unroll
        for (int j = 0; j < 4; ++j)
            bfr[j] = *(const bf16x8*)&Bs[cur + (ncol + j * 16 + fr) * 32 + swz];
#pragma unroll
        for (int i = 0; i < 4; ++i)
#pragma unroll
            for (int j = 0; j < 4; ++j)
                acc[i][j] = __builtin_amdgcn_mfma_f32_16x16x32_bf16(af[i], bfr[j],
                                                                    acc[i][j], 0, 0, 0);
        __syncthreads();
    }
}

#define EPILOGUE_COORDS                                     \
    const int lane = threadIdx.x & 63, wave = threadIdx.x >> 6; \
    const int mrow = (wave >> 1) * 64, ncol = (wave & 1) * 64;  \
    const int col = lane & 15, q = lane >> 4;

#define ACC_INIT                                            \
    floatx4 acc[4][4];                                      \
    _Pragma("unroll") for (int i = 0; i < 4; ++i)           \
        _Pragma("unroll") for (int j = 0; j < 4; ++j)       \
            acc[i][j] = (floatx4){0.f, 0.f, 0.f, 0.f};

// ---------------------------------------------------------------------------
// k_prep: srcb = bf16(src)
// ---------------------------------------------------------------------------
__global__ __launch_bounds__(256) void k_prep(const float* __restrict__ src,
                                              unsigned short* __restrict__ srcb) {
    const size_t idx = ((size_t)blockIdx.x * 256 + threadIdx.x) * 8;
    *(uint4*)&srcb[idx] = cvt8(src + idx);
}

// ---------------------------------------------------------------------------
// k_dstWr: DW[b*dd][d] = SCALE * sum_e dst[b*dd][e] * Wr[d][e]   (128² loop)
// ---------------------------------------------------------------------------
__global__ __launch_bounds__(256) void k_dstWr(const float* __restrict__ dst,
                                               const float* __restrict__ Wr,
                                               unsigned short* __restrict__ DW) {
    __shared__ unsigned short As[2 * 128 * 32];
    __shared__ unsigned short Bs[2 * 128 * 32];
    const int n0 = blockIdx.x * 128, m0 = blockIdx.y * 128;
    ACC_INIT
    mainloop<1, 1>(As, Bs, dst + (size_t)m0 * DIM_, DIM_,
                   Wr + (size_t)n0 * DIM_, DIM_, DIM_ / 32, acc);
    EPILOGUE_COORDS
#pragma unroll
    for (int i = 0; i < 4; ++i)
#pragma unroll
        for (int j = 0; j < 4; ++j)
#pragma unroll
            for (int r = 0; r < 4; ++r)
                DW[(size_t)(m0 + mrow + i * 16 + q * 4 + r) * DIM_ +
                   n0 + ncol + j * 16 + col] = f2bf(acc[i][j][r] * SCALE);
}

// ---------------------------------------------------------------------------
// k_logitsT: LT[dd][s] = exp(DW[dd][:] . srcb[s][:]) -> bf16  (per batch)
// 256² pipelined loop. XCD: b = n&7; s-tile slow. Column sums -> Lpart [B][4][S].
// __launch_bounds__(512,2): cap VGPR at 256 so the 8-wave block always fits.
// ---------------------------------------------------------------------------
__global__ __launch_bounds__(512, 2) void k_logitsT(const unsigned short* __restrict__ DW,
                                                    const unsigned short* __restrict__ srcb,
                                                    unsigned short* __restrict__ LTb,
                                                    float* __restrict__ Lpart) {
    __shared__ __align__(16) unsigned short As[32768];
    __shared__ __align__(16) unsigned short Bs[32768];
    const int n = blockIdx.x;
    const int b = n & 7;          // -> XCD
    const int rem = n >> 3;       // [0,64)
    const int xs = rem >> 2;      // s-tile [0,16), slow (B L2-hot)
    const int yd = rem & 3;       // dd-tile [0,4)
    const int n0 = xs * 256, m0 = yd * 256;
    ACC_INIT8
    mainloop256(As, Bs,
                DW + (size_t)b * DD_ * DIM_ + (size_t)m0 * DIM_, DIM_,
                srcb + (size_t)b * S_ * DIM_ + (size_t)n0 * DIM_, DIM_,
                DIM_ / 64, acc);
    const int t = threadIdx.x, lane = t & 63, w = t >> 6;
    const int wm = w >> 2, wn = w & 3;
    const int c16 = lane & 15, q = lane >> 4;
    const int row0 = m0 + wm * 128, col0 = n0 + wn * 64;
    unsigned short* LT = LTb + (size_t)b * DD_ * S_;
    float psum[4] = {0.f, 0.f, 0.f, 0.f};
#pragma unroll
    for (int i = 0; i < 8; ++i)
#pragma unroll
        for (int j = 0; j < 4; ++j)
#pragma unroll
            for (int r = 0; r < 4; ++r) {
                float e = __expf(acc[i][j][r]);
                LT[(size_t)(row0 + i * 16 + q * 4 + r) * S_ +
                   col0 + j * 16 + c16] = f2bf(e);
                psum[j] += e;
            }
    float* csum = (float*)As;     // [8][256] overlay (buffers dead)
    const int slice = wm * 4 + q;
#pragma unroll
    for (int j = 0; j < 4; ++j)
        csum[slice * 256 + wn * 64 + j * 16 + c16] = psum[j];
    __syncthreads();
    if (t < 256) {
        float v = 0.f;
#pragma unroll
        for (int k = 0; k < 8; ++k) v += csum[k * 256 + t];
        Lpart[((size_t)b * 4 + yd) * S_ + n0 + t] = v;
    }
}

// ---------------------------------------------------------------------------
// k_finalize: scale[b][s] = softplus(state[b][s]) / sum_tiles Lpart (4 slices)
// ---------------------------------------------------------------------------
__global__ __launch_bounds__(256) void k_finalize(const float* __restrict__ state,
                                                  const float* __restrict__ Lpart,
                                                  float* __restrict__ scale) {
    const int i = blockIdx.x * 256 + threadIdx.x;    // flat b*S+s
    const int b = i >> 12, s = i & (S_ - 1);
    float d = 0.f;
#pragma unroll
    for (int k = 0; k < 4; ++k) d += Lpart[((size_t)b * 4 + k) * S_ + s];
    const float st = state[i];
    const float sp = (st > 15.f) ? st : log1pf(__expf(st));
    scale[i] = sp / d;
}

// ---------------------------------------------------------------------------
// k_srcT: srcST[b][d'][s] = bf16( scale[b][s] * srcb[b][s][d'] )
// ---------------------------------------------------------------------------
__global__ __launch_bounds__(256) void k_srcT(const unsigned short* __restrict__ srcb,
                                              const float* __restrict__ scale,
                                              unsigned short* __restrict__ srcST) {
    __shared__ unsigned short Ts[64 * 65];
    const int s0 = blockIdx.x * 64, d0 = blockIdx.y * 64, b = blockIdx.z;
    const int t = threadIdx.x;
    {
        const int r = t >> 2, c0 = (t & 3) * 16;   // r = s-local, c = d'-local
        const unsigned short* g =
            srcb + (size_t)b * S_ * DIM_ + (size_t)(s0 + r) * DIM_ + d0 + c0;
        uint4 v0 = *(const uint4*)g;
        uint4 v1 = *(const uint4*)(g + 8);
        const unsigned short* e0 = (const unsigned short*)&v0;
        const unsigned short* e1 = (const unsigned short*)&v1;
        const float sc = scale[(size_t)b * S_ + s0 + r];
#pragma unroll
        for (int i = 0; i < 8; ++i) {
            Ts[r * 65 + c0 + i]     = f2bf(bf2f(e0[i]) * sc);
            Ts[r * 65 + c0 + 8 + i] = f2bf(bf2f(e1[i]) * sc);
        }
    }
    __syncthreads();
    {
        const int rr = t >> 2, c0 = (t & 3) * 16;  // rr = d'-local, c = s-local
        unsigned short tmp[16];
#pragma unroll
        for (int j = 0; j < 16; ++j) tmp[j] = Ts[(c0 + j) * 65 + rr];
        unsigned short* o =
            srcST + (size_t)b * DIM_ * S_ + (size_t)(d0 + rr) * S_ + s0 + c0;
        *(uint4*)o = *(const uint4*)tmp;
        *(uint4*)(o + 8) = *(const uint4*)(tmp + 8);
    }
}

// ---------------------------------------------------------------------------
// k_dstate: delta_state[b][dd] = sum_s LT[dd][s] * scale[b][s] * state[b][s]
// ---------------------------------------------------------------------------
__global__ __launch_bounds__(256) void k_dstate(const unsigned short* __restrict__ LT,
                                                const float* __restrict__ state,
                                                const float* __restrict__ scale,
                                                float* __restrict__ out) {
    const int b = blockIdx.y;
    const int dd = blockIdx.x * 4 + (threadIdx.x >> 6);
    const int lane = threadIdx.x & 63;
    const unsigned short* row = LT + (size_t)b * DD_ * S_ + (size_t)dd * S_;
    const float* st = state + (size_t)b * S_;
    const float* sc = scale + (size_t)b * S_;

    float acc = 0.f;
#pragma unroll
    for (int it = 0; it < S_ / 512; ++it) {
        const int s = it * 512 + lane * 8;
        uint4 v = *(const uint4*)(row + s);
        const unsigned short* e = (const unsigned short*)&v;
        float4 f0 = *(const float4*)(st + s);
        float4 f1 = *(const float4*)(st + s + 4);
        float4 c0 = *(const float4*)(sc + s);
        float4 c1 = *(const float4*)(sc + s + 4);
        acc += bf2f(e[0]) * f0.x * c0.x + bf2f(e[1]) * f0.y * c0.y +
               bf2f(e[2]) * f0.z * c0.z + bf2f(e[3]) * f0.w * c0.w +
               bf2f(e[4]) * f1.x * c1.x + bf2f(e[5]) * f1.y * c1.y +
               bf2f(e[6]) * f1.z * c1.z + bf2f(e[7]) * f1.w * c1.w;
    }
#pragma unroll
    for (int off = 32; off; off >>= 1) acc += __shfl_down(acc, off);
    if (lane == 0) out[(size_t)b * DD_ + dd] = acc;
}

// ---------------------------------------------------------------------------
// k_dU: partial[ks][b][dd][d'] = sum_{s slice} LT[dd][s]*srcST[d'][s], fp16
// 256² pipelined loop, split-K=4; all 8 tiles of one (b,ks) on one XCD.
// __launch_bounds__(512,2): cap VGPR at 256 so the 8-wave block always fits.
// ---------------------------------------------------------------------------
__global__ __launch_bounds__(512, 2) void k_dU(const unsigned short* __restrict__ LTb,
                                               const unsigned short* __restrict__ srcST,
                                               __half* __restrict__ Pp) {
    __shared__ __align__(16) unsigned short As[32768];
    __shared__ __align__(16) unsigned short Bs[32768];
    const int n = blockIdx.x;                 // [0,256)
    const int qn = n >> 3;                    // [0,32)
    const int tile = qn & 7, zhi = qn >> 3;   // tile [0,8), zhi [0,4)
    const int z = (n & 7) + 8 * zhi;          // (b,ks) [0,32); XCD = n&7 = z&7
    const int b = z >> 2, ks = z & 3;
    const int xe = tile >> 2;                 // d'-tile [0,2)
    const int yd = tile & 3;                  // dd-tile [0,4)
    const int n0 = xe * 256, m0 = yd * 256;
    ACC_INIT8
    mainloop256(As, Bs,
                LTb + (size_t)b * DD_ * S_ + (size_t)m0 * S_ + ks * 1024, S_,
                srcST + (size_t)b * DIM_ * S_ + (size_t)n0 * S_ + ks * 1024, S_,
                1024 / 64, acc);
    const int t = threadIdx.x, lane = t & 63, w = t >> 6;
    const int wm = w >> 2, wn = w & 3;
    const int c16 = lane & 15, q = lane >> 4;
    const int row0 = m0 + wm * 128, col0 = n0 + wn * 64;
    __half* O = Pp + (size_t)ks * B_ * DD_ * DIM_ + (size_t)b * DD_ * DIM_;
#pragma unroll
    for (int i = 0; i < 8; ++i)
#pragma unroll
        for (int j = 0; j < 4; ++j)
#pragma unroll
            for (int r = 0; r < 4; ++r)
                O[(size_t)(row0 + i * 16 + q * 4 + r) * DIM_ +
                  col0 + j * 16 + c16] = __float2half(acc[i][j][r]);
}

// ---------------------------------------------------------------------------
// k_reduceU: blocks [0,2048): U bf16 = sum of 4 fp16 partial slices
//            blocks [2048,2112): WvT[e][d] = bf16(Wv[d][e]) transpose
// ---------------------------------------------------------------------------
__global__ __launch_bounds__(256) void k_reduceU(const __half* __restrict__ Pp,
                                                 unsigned short* __restrict__ U,
                                                 const float* __restrict__ Wv,
                                                 unsigned short* __restrict__ WvT) {
    __shared__ float Ts[64 * 68];
    const int t = threadIdx.x;
    if (blockIdx.x < 2048) {
        const size_t idx = ((size_t)blockIdx.x * 256 + t) * 8;
        const size_t n = (size_t)B_ * DD_ * DIM_;
        float o[8] = {0.f, 0.f, 0.f, 0.f, 0.f, 0.f, 0.f, 0.f};
#pragma unroll
        for (int ks = 0; ks < 4; ++ks) {
            uint4 v = *(const uint4*)(Pp + (size_t)ks * n + idx);
            const __half* h = (const __half*)&v;
#pragma unroll
            for (int j = 0; j < 8; ++j) o[j] += __half2float(h[j]);
        }
        unsigned short tmp[8];
#pragma unroll
        for (int j = 0; j < 8; ++j) tmp[j] = f2bf(o[j]);
        *(uint4*)&U[idx] = *(const uint4*)tmp;
        return;
    }
    const int n2 = blockIdx.x - 2048;
    const int d0 = (n2 & 7) * 64, e0 = (n2 >> 3) * 64;
    {
        const int r = t >> 2, c0 = (t & 3) * 16;
        const float* g = Wv + (size_t)(d0 + r) * DIM_ + e0 + c0;
#pragma unroll
        for (int i = 0; i < 4; ++i)
            *(float4*)&Ts[r * 68 + c0 + i * 4] = *(const float4*)(g + i * 4);
    }
    __syncthreads();
    {
        const int rr = t >> 2, c0 = (t & 3) * 16;
        unsigned short tmp[16];
#pragma unroll
        for (int j = 0; j < 16; ++j) tmp[j] = f2bf(Ts[(c0 + j) * 68 + rr]);
        unsigned short* o = WvT + (size_t)(e0 + rr) * DIM_ + d0 + c0;
        *(uint4*)o = *(const uint4*)tmp;
        *(uint4*)(o + 8) = *(const uint4*)(tmp + 8);
    }
}

// ---------------------------------------------------------------------------
// k_dvalW: d_val[b*dd][e] = sum_d' U[b*dd][d'] * WvT[e][d']   (fp32 out, 128²)
// ---------------------------------------------------------------------------
__global__ __launch_bounds__(256) void k_dvalW(const unsigned short* __restrict__ U,
                                               const unsigned short* __restrict__ WvT,
                                               float* __restrict__ d_val) {
    __shared__ unsigned short As[2 * 128 * 32];
    __shared__ unsigned short Bs[2 * 128 * 32];
    const int n0 = blockIdx.x * 128, m0 = blockIdx.y * 128;
    ACC_INIT
    mainloop<0, 0>(As, Bs, U + (size_t)m0 * DIM_, DIM_,
                   WvT + (size_t)n0 * DIM_, DIM_, DIM_ / 32, acc);
    EPILOGUE_COORDS
#pragma unroll
    for (int i = 0; i < 4; ++i)
#pragma unroll
        for (int j = 0; j < 4; ++j)
#pragma unroll
            for (int r = 0; r < 4; ++r)
                d_val[(size_t)(m0 + mrow + i * 16 + q * 4 + r) * DIM_ +
                      n0 + ncol + j * 16 + col] = acc[i][j][r];
}

// ---------------------------------------------------------------------------
extern "C" void kernel_launch(void* const* d_in, const int* in_sizes, int n_in,
                              void* d_out, int out_size, void* d_ws, size_t ws_size,
                              hipStream_t stream) {
    const float* src   = (const float*)d_in[0];   // [B,S,DIM]
    const float* state = (const float*)d_in[1];   // [B,S]
    const float* dst   = (const float*)d_in[2];   // [B,D,DIM]
    const float* Wr    = (const float*)d_in[3];   // [DIM,DIM]
    const float* Wv    = (const float*)d_in[4];   // [DIM,DIM]

    // ws layout (128 MiB):
    //  A [0,32):  srcb bf16 (prep -> srcT); late: Pp fp16 4x8MiB (dU -> reduceU)
    //  B [32,96): LT bf16 (logitsT -> dU); late: U bf16 (8) + WvT (.5)
    //  C [96,128): early: DW(8) Lpart(.5); late: srcST (32, srcT -> dU)
    //  scale parks in d_out's d_val region (overwritten by k_dvalW at the end)
    unsigned short* srcb = (unsigned short*)d_ws;
    __half* Pp = (__half*)d_ws;
    unsigned short* LT = srcb + (size_t)B_ * S_ * DIM_;
    unsigned short* U  = LT;                                   // overlays dead LT
    unsigned short* WvT = U + (size_t)B_ * DD_ * DIM_;
    unsigned short* C = LT + (size_t)B_ * DD_ * S_;
    unsigned short* DW = C;
    float* Lpart = (float*)(DW + (size_t)B_ * DD_ * DIM_);     // [B][4][S]
    unsigned short* srcST = C;                                 // overlays dead DW/Lpart

    float* d_state = (float*)d_out;               // [B, DD]
    float* d_val   = (float*)d_out + B_ * DD_;    // [B, DD, DIM]
    float* scale   = d_val;                       // park (dead before k_dvalW writes)

    k_prep<<<dim3(8192), 256, 0, stream>>>(src, srcb);
    k_dstWr<<<dim3(DIM_ / 128, (B_ * DD_) / 128), 256, 0, stream>>>(dst, Wr, DW);
    k_logitsT<<<dim3(512), 512, 0, stream>>>(DW, srcb, LT, Lpart);
    k_finalize<<<dim3((B_ * S_) / 256), 256, 0, stream>>>(state, Lpart, scale);
    k_dstate<<<dim3(DD_ / 4, B_), 256, 0, stream>>>(LT, state, scale, d_state);
    k_srcT<<<dim3(S_ / 64, DIM_ / 64, B_), 256, 0, stream>>>(srcb, scale, srcST);
    k_dU<<<dim3(256), 512, 0, stream>>>(LT, srcST, Pp);
    k_reduceU<<<dim3(2048 + 64), 256, 0, stream>>>(Pp, U, Wv, WvT);
    k_dvalW<<<dim3(DIM_ / 128, (B_ * DD_) / 128), 256, 0, stream>>>(U, WvT, d_val);
}